// Round 1
// baseline (868.012 us; speedup 1.0000x reference)
//
#include <hip/hip_runtime.h>
#include <math.h>

#define NB   1152
#define NTOK 64
#define NC   384
#define NH   12
#define NDH  32

typedef short short8 __attribute__((ext_vector_type(8)));
typedef float f32x4  __attribute__((ext_vector_type(4)));

__device__ __forceinline__ unsigned short f2bf(float f) {
    unsigned int u = __builtin_bit_cast(unsigned int, f);
    unsigned int r = u + 0x7fffu + ((u >> 16) & 1u);   // RNE
    return (unsigned short)(r >> 16);
}
__device__ __forceinline__ unsigned int pack2(float lo, float hi) {
    return (unsigned int)f2bf(lo) | ((unsigned int)f2bf(hi) << 16);
}
__device__ __forceinline__ float bf2f(unsigned short h) {
    return __builtin_bit_cast(float, (unsigned int)h << 16);
}
__device__ __forceinline__ f32x4 mfma_bf16(short8 a, short8 b, f32x4 c) {
    return __builtin_amdgcn_mfma_f32_16x16x32_bf16(a, b, c, 0, 0, 0);
}

// XOR-swizzled 64x384 bf16 tile (no padding, 2-way-free bank pattern).
// Element (row, k): group g = k/8 is XORed with (row&7) at 16B granularity.
__device__ __forceinline__ short8 tile_afrag(const unsigned short* t, int row, int kq) {
    return *(const short8*)((const char*)t + row * 768 + ((kq ^ (row & 7)) << 4));
}

// ---------------------------------------------------------------------------
// prep: transpose+convert weights to bf16 col-major (B-operand layout).
//   wT[col 0..1151][k 0..383]  (cols: 0..383 wq, 384..767 wk, 768..1151 wv)
//   wprojT[col 0..383][k 0..383]
// ---------------------------------------------------------------------------
__global__ __launch_bounds__(256) void prep_kernel(
    const float* __restrict__ wq, const float* __restrict__ wk,
    const float* __restrict__ wv, const float* __restrict__ wproj,
    unsigned int* __restrict__ wT, unsigned int* __restrict__ wprojT)
{
    const int o2 = blockIdx.x * 256 + threadIdx.x;
    if (o2 < 221184) {
        const int col = o2 / 192, k2 = o2 % 192, k = k2 * 2;
        const float* src = (col < 384) ? wq : ((col < 768) ? wk : wv);
        const int c = (col < 384) ? col : ((col < 768) ? col - 384 : col - 768);
        const float a = src[(size_t)k * NC + c];
        const float b = src[(size_t)(k + 1) * NC + c];
        wT[col * 192 + k2] = pack2(a, b);
    } else {
        const int o = o2 - 221184;
        const int col = o / 192, k2 = o % 192, k = k2 * 2;
        const float a = wproj[(size_t)k * NC + col];
        const float b = wproj[(size_t)(k + 1) * NC + col];
        wprojT[col * 192 + k2] = pack2(a, b);
    }
}

// ---------------------------------------------------------------------------
// cpb MLP: 225 blocks x 1 wave; lane handles 8 hidden units, shfl-reduce.
// Writes tbs[225][12] (fp32) to workspace.
// ---------------------------------------------------------------------------
__global__ __launch_bounds__(64) void cpb_mlp_kernel(
    const float* __restrict__ w1, const float* __restrict__ b1,
    const float* __restrict__ w2, const float* __restrict__ b2,
    float* __restrict__ tbs)
{
    const int p = blockIdx.x;           // 0..224
    const int lane = threadIdx.x;       // 0..63
    const int ip = p / 15, jp = p % 15;
    float u0 = (float)(jp - 7) * (8.0f / 7.0f);
    float u1 = (float)(ip - 7) * (8.0f / 7.0f);
    float s0 = (u0 > 0.f) ? 1.f : ((u0 < 0.f) ? -1.f : 0.f);
    float s1 = (u1 > 0.f) ? 1.f : ((u1 < 0.f) ? -1.f : 0.f);
    float in0 = s0 * log2f(fabsf(u0) + 1.0f) * (1.0f / 3.0f);
    float in1 = s1 * log2f(fabsf(u1) + 1.0f) * (1.0f / 3.0f);

    float a[12];
    #pragma unroll
    for (int m = 0; m < 12; ++m) a[m] = 0.f;
    #pragma unroll
    for (int e = 0; e < 8; ++e) {
        const int j = lane * 8 + e;
        float hh = fmaxf(in0 * w1[j] + in1 * w1[512 + j] + b1[j], 0.0f);
        #pragma unroll
        for (int m = 0; m < 12; ++m) a[m] += hh * w2[j * 12 + m];
    }
    #pragma unroll
    for (int m = 0; m < 12; ++m) {
        #pragma unroll
        for (int off = 1; off < 64; off <<= 1) a[m] += __shfl_xor(a[m], off, 64);
    }
    if (lane < 12) tbs[p * 12 + lane] = a[lane] + b2[lane];
}

// bias gather: bias[h][ti][tj] = 16*sigmoid(tbs[relidx(ti,tj)][h])
__global__ __launch_bounds__(1024) void bias_gather_kernel(
    const float* __restrict__ tbs, float* __restrict__ bias)
{
    const int i = blockIdx.x * 1024 + threadIdx.x;
    if (i >= NH * NTOK * NTOK) return;
    const int h = i >> 12, rem = i & 4095;
    const int ti = rem >> 6, tj = rem & 63;
    const int dr = (ti >> 3) - (tj >> 3);
    const int dc = (ti & 7) - (tj & 7);
    const int p = (dr + 7) * 15 + (dc + 7);
    bias[i] = 16.0f / (1.0f + __expf(-tbs[p * 12 + h]));
}

// ---------------------------------------------------------------------------
// attn: fused per-window QKV (MFMA) + cosine attention (MFMA S & PV).
// 1152 blocks x 512 threads (8 waves). 2 heads per iteration, 6 iterations.
// Wave w: m-tile (w&3), head-slot (w>>2). Norms computed in registers during
// scatter (no norms phase/barrier); softmax denominators stay in registers
// (S-wave rows == PV-wave rows). 4 barriers per iteration.
// LDS ~79.9 KB -> 2 blocks/CU (gfx950: 160 KB/CU) = 16 waves/CU.
// ---------------------------------------------------------------------------
__global__ __launch_bounds__(512, 4) void attn_kernel(
    const float* __restrict__ x,    const float* __restrict__ mask,
    const float* __restrict__ bq,   const float* __restrict__ bv,
    const float* __restrict__ tau,  const unsigned short* __restrict__ wT,
    const float* __restrict__ bias, float* __restrict__ out)
{
    __shared__ unsigned short xs[64 * 384];     // 49152 B, swizzled
    __shared__ unsigned short qk2[2][5120];     // per head: qs[64*40] | ks[64*40]; Ps aliases
    __shared__ unsigned short vT2[2][32 * 72];  // per head: v transposed [d][token]
    __shared__ float qn2[2][64];
    __shared__ float kn2[2][64];

    const int tid  = threadIdx.x;
    const int b    = blockIdx.x;
    const int w    = tid >> 6;        // 0..7
    const int lane = tid & 63;
    const int quad = lane >> 4;
    const int lq   = lane & 15;
    const int mt   = w & 3;           // m-tile (16 rows)
    const int hw   = w >> 2;          // head slot 0..1
    const int t0   = mt * 16 + quad * 4;

    unsigned int* xsu = (unsigned int*)xs;

    // ---- stage x once: 64 tok x 384 k, fp32 -> bf16, swizzled ----
    {
        const int row = tid >> 3;             // 0..63
        const int t8  = tid & 7;              // 0..7
        const float* xr = &x[((size_t)b * NTOK + row) * NC];
        #pragma unroll
        for (int e = 0; e < 12; ++e) {
            const float4 xv = *(const float4*)&xr[(t8 + e * 8) * 4];
            const int p = (t8 + e * 8) * 2;   // uint index within row (unswizzled)
            const int g = p >> 2;
            const int u = row * 192 + (((g ^ (row & 7)) << 2) | (p & 3));
            uint2 w2;
            w2.x = pack2(xv.x, xv.y);
            w2.y = pack2(xv.z, xv.w);
            *(uint2*)&xsu[u] = w2;
        }
    }
    __syncthreads();

    unsigned short* qs_h = qk2[hw];
    unsigned short* ks_h = qk2[hw] + 2560;
    unsigned short* Ps_h = qk2[hw];           // alias (qs/ks dead when P written)
    unsigned short* vT_h = vT2[hw];

    for (int it = 0; it < 6; ++it) {
        const int h = it * 2 + hw;

        // ---------- QKV: this wave computes its head's q|k|v cols for its m-tile ----------
        f32x4 acc[6];
        #pragma unroll
        for (int j = 0; j < 6; ++j) acc[j] = (f32x4){0.f, 0.f, 0.f, 0.f};

        const unsigned short* bp[6];
        #pragma unroll
        for (int j = 0; j < 6; ++j) {
            // j: 0,1 = q halves; 2,3 = k halves; 4,5 = v halves
            const int col = (j >> 1) * 384 + h * 32 + (j & 1) * 16 + lq;
            bp[j] = wT + (size_t)col * NC + quad * 8;
        }

        for (int ksI = 0; ksI < 12; ++ksI) {
            const short8 a = tile_afrag(xs, mt * 16 + lq, ksI * 4 + quad);
            #pragma unroll
            for (int j = 0; j < 6; ++j)
                acc[j] = mfma_bf16(a, *(const short8*)&bp[j][ksI * 32], acc[j]);
        }

        // ---------- prefetch bias+mask for this wave's S tile (hidden by scatter) ----------
        float biasv[4][4], maskv[4][4];
        #pragma unroll
        for (int nt = 0; nt < 4; ++nt)
            #pragma unroll
            for (int r = 0; r < 4; ++r) {
                const int row = t0 + r, col = nt * 16 + lq;
                biasv[nt][r] = bias[h * 4096 + row * 64 + col];
                maskv[nt][r] = mask[(size_t)b * 4096 + row * 64 + col];
            }

        __syncthreads();   // WAR: prior iteration's PV reads of Ps/vT complete

        // ---------- scatter q/k/v (+biases) with in-register norms ----------
        float qnl[4];
        {
            const float bq0 = bq[h * 32 + lq], bq1 = bq[h * 32 + 16 + lq];
            const float bv0 = bv[h * 32 + lq], bv1 = bv[h * 32 + 16 + lq];

            float qred[4], kred[4];
            #pragma unroll
            for (int r = 0; r < 4; ++r) {
                const float q0 = acc[0][r] + bq0, q1 = acc[1][r] + bq1;
                qs_h[(t0 + r) * 40 + lq]      = f2bf(q0);
                qs_h[(t0 + r) * 40 + 16 + lq] = f2bf(q1);
                ks_h[(t0 + r) * 40 + lq]      = f2bf(acc[2][r]);
                ks_h[(t0 + r) * 40 + 16 + lq] = f2bf(acc[3][r]);
                qred[r] = q0 * q0 + q1 * q1;
                kred[r] = acc[2][r] * acc[2][r] + acc[3][r] * acc[3][r];
            }
            uint2 u2;
            u2.x = pack2(acc[4][0] + bv0, acc[4][1] + bv0);
            u2.y = pack2(acc[4][2] + bv0, acc[4][3] + bv0);
            *(uint2*)&vT_h[lq * 72 + t0] = u2;
            u2.x = pack2(acc[5][0] + bv1, acc[5][1] + bv1);
            u2.y = pack2(acc[5][2] + bv1, acc[5][3] + bv1);
            *(uint2*)&vT_h[(16 + lq) * 72 + t0] = u2;

            // row norms: reduce q0^2+q1^2 (and k) across the 16-lane lq group
            #pragma unroll
            for (int r = 0; r < 4; ++r) {
                #pragma unroll
                for (int off = 1; off < 16; off <<= 1) {
                    qred[r] += __shfl_xor(qred[r], off, 64);
                    kred[r] += __shfl_xor(kred[r], off, 64);
                }
                qnl[r] = sqrtf(qred[r]);
            }
            if (lq == 0) {
                #pragma unroll
                for (int r = 0; r < 4; ++r) {
                    qn2[hw][t0 + r] = qnl[r];
                    kn2[hw][t0 + r] = sqrtf(kred[r]);
                }
            }
        }
        __syncthreads();

        // ---------- S = q @ kT (wave owns m-tile mt of head h) ----------
        const float ls = fmaxf(tau[h] + 2.302585093f, 0.01f);
        const short8 aq = *(const short8*)&qs_h[(mt * 16 + lq) * 40 + quad * 8];
        float svf[4][4];
        #pragma unroll
        for (int nt = 0; nt < 4; ++nt) {
            const short8 bk = *(const short8*)&ks_h[(nt * 16 + lq) * 40 + quad * 8];
            const f32x4 sv = mfma_bf16(aq, bk, (f32x4){0.f, 0.f, 0.f, 0.f});
            const float knc = kn2[hw][nt * 16 + lq];
            #pragma unroll
            for (int r = 0; r < 4; ++r) {
                const float den = fmaxf(qnl[r] * knc, 1e-6f);
                svf[nt][r] = sv[r] / den * ls + biasv[nt][r] + maskv[nt][r];
            }
        }

        // softmax across the 16-lane lq group (cols live in lq x nt)
        float mx[4], sm[4];
        #pragma unroll
        for (int r = 0; r < 4; ++r) {
            float m = fmaxf(fmaxf(svf[0][r], svf[1][r]), fmaxf(svf[2][r], svf[3][r]));
            #pragma unroll
            for (int off = 1; off < 16; off <<= 1) m = fmaxf(m, __shfl_xor(m, off, 64));
            mx[r] = m; sm[r] = 0.f;
        }
        #pragma unroll
        for (int nt = 0; nt < 4; ++nt)
            #pragma unroll
            for (int r = 0; r < 4; ++r) {
                const float e = __expf(svf[nt][r] - mx[r]);
                svf[nt][r] = e; sm[r] += e;
            }
        #pragma unroll
        for (int r = 0; r < 4; ++r) {
            #pragma unroll
            for (int off = 1; off < 16; off <<= 1) sm[r] += __shfl_xor(sm[r], off, 64);
        }

        __syncthreads();   // all S reads of qs/ks done before Ps overwrite

        #pragma unroll
        for (int nt = 0; nt < 4; ++nt)
            #pragma unroll
            for (int r = 0; r < 4; ++r)
                Ps_h[(t0 + r) * 72 + nt * 16 + lq] = f2bf(svf[nt][r]);
        __syncthreads();

        // ---------- O = P @ v (same rows as S phase: sm stays in registers) ----------
        f32x4 oa[2];
        oa[0] = (f32x4){0.f, 0.f, 0.f, 0.f};
        oa[1] = (f32x4){0.f, 0.f, 0.f, 0.f};
        #pragma unroll
        for (int st = 0; st < 2; ++st) {
            const short8 ap = *(const short8*)&Ps_h[(mt * 16 + lq) * 72 + st * 32 + quad * 8];
            #pragma unroll
            for (int n = 0; n < 2; ++n) {
                const short8 bv_ = *(const short8*)&vT_h[(n * 16 + lq) * 72 + st * 32 + quad * 8];
                oa[n] = mfma_bf16(ap, bv_, oa[n]);
            }
        }
        float rsi[4];
        #pragma unroll
        for (int r = 0; r < 4; ++r) rsi[r] = 1.0f / sm[r];
        #pragma unroll
        for (int n = 0; n < 2; ++n)
            #pragma unroll
            for (int r = 0; r < 4; ++r)
                out[((size_t)b * NTOK + t0 + r) * NC + h * 32 + n * 16 + lq] = oa[n][r] * rsi[r];
    }
}

// ---------------------------------------------------------------------------
// proj: out = out @ wproj + bproj, in-place. 1152 blocks x 256.
// Stage 64x384 tile once (swizzled bf16), then 288 MFMAs/wave barrier-free.
// ---------------------------------------------------------------------------
__global__ __launch_bounds__(256) void proj_kernel(
    const unsigned short* __restrict__ wprojT, const float* __restrict__ bproj,
    float* __restrict__ out)
{
    __shared__ unsigned short as_[64 * 384];  // 49152 B, swizzled
    unsigned int* asu = (unsigned int*)as_;

    const int tid  = threadIdx.x;
    const size_t r0 = (size_t)blockIdx.x * 64;
    const int w    = tid >> 6;
    const int lane = tid & 63;
    const int quad = lane >> 4;
    const int lq   = lane & 15;

    {
        const int row = tid >> 2;
        const int q4  = tid & 3;
        const float* xr = &out[(r0 + row) * NC + q4 * 96];
        #pragma unroll
        for (int e = 0; e < 24; ++e) {
            const float4 xv = *(const float4*)&xr[e * 4];
            const int p = q4 * 48 + e * 2;
            const int g = p >> 2;
            const int u = row * 192 + (((g ^ (row & 7)) << 2) | (p & 3));
            uint2 w2;
            w2.x = pack2(xv.x, xv.y);
            w2.y = pack2(xv.z, xv.w);
            *(uint2*)&asu[u] = w2;
        }
    }
    __syncthreads();

    f32x4 acc[4][6];
    #pragma unroll
    for (int mt = 0; mt < 4; ++mt)
        #pragma unroll
        for (int n = 0; n < 6; ++n) acc[mt][n] = (f32x4){0.f, 0.f, 0.f, 0.f};

    const unsigned short* bp[6];
    #pragma unroll
    for (int n = 0; n < 6; ++n)
        bp[n] = wprojT + (size_t)(w * 96 + n * 16 + lq) * NC + quad * 8;

    for (int ksI = 0; ksI < 12; ++ksI) {
        short8 am[4];
        #pragma unroll
        for (int mt = 0; mt < 4; ++mt)
            am[mt] = tile_afrag(as_, mt * 16 + lq, ksI * 4 + quad);
        #pragma unroll
        for (int n = 0; n < 6; ++n) {
            const short8 bb = *(const short8*)&bp[n][ksI * 32];
            #pragma unroll
            for (int mt = 0; mt < 4; ++mt) acc[mt][n] = mfma_bf16(am[mt], bb, acc[mt][n]);
        }
    }

    float bpv[6];
    #pragma unroll
    for (int n = 0; n < 6; ++n) bpv[n] = bproj[w * 96 + n * 16 + lq];
    #pragma unroll
    for (int mt = 0; mt < 4; ++mt)
        #pragma unroll
        for (int n = 0; n < 6; ++n)
            #pragma unroll
            for (int r = 0; r < 4; ++r)
                out[(r0 + mt * 16 + quad * 4 + r) * NC + w * 96 + n * 16 + lq]
                    = acc[mt][n][r] + bpv[n];
}

// ---------------------------------------------------------------------------
extern "C" void kernel_launch(void* const* d_in, const int* in_sizes, int n_in,
                              void* d_out, int out_size, void* d_ws, size_t ws_size,
                              hipStream_t stream) {
    (void)in_sizes; (void)n_in; (void)out_size; (void)ws_size;
    const float* x     = (const float*)d_in[0];
    const float* mask  = (const float*)d_in[1];
    const float* wq    = (const float*)d_in[2];
    const float* bq    = (const float*)d_in[3];
    const float* wk    = (const float*)d_in[4];
    const float* wv    = (const float*)d_in[5];
    const float* bv    = (const float*)d_in[6];
    const float* w1    = (const float*)d_in[7];
    const float* b1    = (const float*)d_in[8];
    const float* w2    = (const float*)d_in[9];
    const float* b2    = (const float*)d_in[10];
    const float* tau   = (const float*)d_in[11];
    const float* wproj = (const float*)d_in[12];
    const float* bproj = (const float*)d_in[13];
    float* out = (float*)d_out;

    // ws: wT 884736 | wprojT 294912 | bias 196608 | tbs 10800  (~1.39 MB)
    unsigned short* wT     = (unsigned short*)d_ws;
    unsigned short* wprojT = (unsigned short*)((char*)d_ws + 884736);
    float*          bias   = (float*)((char*)d_ws + 884736 + 294912);
    float*          tbs    = (float*)((char*)d_ws + 884736 + 294912 + 196608);

    prep_kernel<<<1152, 256, 0, stream>>>(wq, wk, wv, wproj,
                                          (unsigned int*)wT, (unsigned int*)wprojT);
    cpb_mlp_kernel<<<225, 64, 0, stream>>>(w1, b1, w2, b2, tbs);
    bias_gather_kernel<<<48, 1024, 0, stream>>>(tbs, bias);
    attn_kernel<<<NB, 512, 0, stream>>>(x, mask, bq, bv, tau, wT, bias, out);
    proj_kernel<<<NB, 256, 0, stream>>>(wprojT, bproj, out);
}

// Round 2
// 852.389 us; speedup vs baseline: 1.0183x; 1.0183x over previous
//
#include <hip/hip_runtime.h>
#include <math.h>

#define NB   1152
#define NTOK 64
#define NC   384
#define NH   12
#define NDH  32

typedef short short8 __attribute__((ext_vector_type(8)));
typedef float f32x4  __attribute__((ext_vector_type(4)));

__device__ __forceinline__ unsigned short f2bf(float f) {
    unsigned int u = __builtin_bit_cast(unsigned int, f);
    unsigned int r = u + 0x7fffu + ((u >> 16) & 1u);   // RNE
    return (unsigned short)(r >> 16);
}
__device__ __forceinline__ unsigned int pack2(float lo, float hi) {
    return (unsigned int)f2bf(lo) | ((unsigned int)f2bf(hi) << 16);
}
__device__ __forceinline__ float bf2f(unsigned short h) {
    return __builtin_bit_cast(float, (unsigned int)h << 16);
}
__device__ __forceinline__ f32x4 mfma_bf16(short8 a, short8 b, f32x4 c) {
    return __builtin_amdgcn_mfma_f32_16x16x32_bf16(a, b, c, 0, 0, 0);
}

// XOR-swizzled 64x384 bf16 tile (no padding, 2-way-free bank pattern).
// Element (row, k): group g = k/8 is XORed with (row&7) at 16B granularity.
__device__ __forceinline__ short8 tile_afrag(const unsigned short* t, int row, int kq) {
    return *(const short8*)((const char*)t + row * 768 + ((kq ^ (row & 7)) << 4));
}

// ---------------------------------------------------------------------------
// prep: transpose+convert weights to bf16 col-major (B-operand layout).
//   wT[col 0..1151][k 0..383]  (cols: 0..383 wq, 384..767 wk, 768..1151 wv)
//   wprojT[col 0..383][k 0..383]
// ---------------------------------------------------------------------------
__global__ __launch_bounds__(256) void prep_kernel(
    const float* __restrict__ wq, const float* __restrict__ wk,
    const float* __restrict__ wv, const float* __restrict__ wproj,
    unsigned int* __restrict__ wT, unsigned int* __restrict__ wprojT)
{
    const int o2 = blockIdx.x * 256 + threadIdx.x;
    if (o2 < 221184) {
        const int col = o2 / 192, k2 = o2 % 192, k = k2 * 2;
        const float* src = (col < 384) ? wq : ((col < 768) ? wk : wv);
        const int c = (col < 384) ? col : ((col < 768) ? col - 384 : col - 768);
        const float a = src[(size_t)k * NC + c];
        const float b = src[(size_t)(k + 1) * NC + c];
        wT[col * 192 + k2] = pack2(a, b);
    } else {
        const int o = o2 - 221184;
        const int col = o / 192, k2 = o % 192, k = k2 * 2;
        const float a = wproj[(size_t)k * NC + col];
        const float b = wproj[(size_t)(k + 1) * NC + col];
        wprojT[col * 192 + k2] = pack2(a, b);
    }
}

// ---------------------------------------------------------------------------
// cpb MLP: 225 blocks x 1 wave; lane handles 8 hidden units, shfl-reduce.
// Writes tbs[225][12] (fp32) to workspace.
// ---------------------------------------------------------------------------
__global__ __launch_bounds__(64) void cpb_mlp_kernel(
    const float* __restrict__ w1, const float* __restrict__ b1,
    const float* __restrict__ w2, const float* __restrict__ b2,
    float* __restrict__ tbs)
{
    const int p = blockIdx.x;           // 0..224
    const int lane = threadIdx.x;       // 0..63
    const int ip = p / 15, jp = p % 15;
    float u0 = (float)(jp - 7) * (8.0f / 7.0f);
    float u1 = (float)(ip - 7) * (8.0f / 7.0f);
    float s0 = (u0 > 0.f) ? 1.f : ((u0 < 0.f) ? -1.f : 0.f);
    float s1 = (u1 > 0.f) ? 1.f : ((u1 < 0.f) ? -1.f : 0.f);
    float in0 = s0 * log2f(fabsf(u0) + 1.0f) * (1.0f / 3.0f);
    float in1 = s1 * log2f(fabsf(u1) + 1.0f) * (1.0f / 3.0f);

    float a[12];
    #pragma unroll
    for (int m = 0; m < 12; ++m) a[m] = 0.f;
    #pragma unroll
    for (int e = 0; e < 8; ++e) {
        const int j = lane * 8 + e;
        float hh = fmaxf(in0 * w1[j] + in1 * w1[512 + j] + b1[j], 0.0f);
        #pragma unroll
        for (int m = 0; m < 12; ++m) a[m] += hh * w2[j * 12 + m];
    }
    #pragma unroll
    for (int m = 0; m < 12; ++m) {
        #pragma unroll
        for (int off = 1; off < 64; off <<= 1) a[m] += __shfl_xor(a[m], off, 64);
    }
    if (lane < 12) tbs[p * 12 + lane] = a[lane] + b2[lane];
}

// bias gather: bias[h][ti][tj] = 16*sigmoid(tbs[relidx(ti,tj)][h])
__global__ __launch_bounds__(1024) void bias_gather_kernel(
    const float* __restrict__ tbs, float* __restrict__ bias)
{
    const int i = blockIdx.x * 1024 + threadIdx.x;
    if (i >= NH * NTOK * NTOK) return;
    const int h = i >> 12, rem = i & 4095;
    const int ti = rem >> 6, tj = rem & 63;
    const int dr = (ti >> 3) - (tj >> 3);
    const int dc = (ti & 7) - (tj & 7);
    const int p = (dr + 7) * 15 + (dc + 7);
    bias[i] = 16.0f / (1.0f + __expf(-tbs[p * 12 + h]));
}

// ---------------------------------------------------------------------------
// attn: fused per-window QKV (MFMA) + cosine attention (MFMA S & PV).
// 1152 blocks x 512 threads (8 waves). 2 heads per iteration, 6 iterations.
// Wave w: m-tile (w&3), head-slot (w>>2). Norms in registers during scatter;
// softmax denominators stay in registers; mask hoisted out of the head loop
// (head-invariant per wave). 3 barriers per iteration (Ps->PV needs none:
// each wave reads only its own Ps rows).
// LDS ~79.9 KB -> 2 blocks/CU; __launch_bounds__(512,2) -> VGPR cap 128
// (the (512,4) variant capped at 64 and spilled: R1 regression).
// ---------------------------------------------------------------------------
__global__ __launch_bounds__(512, 2) void attn_kernel(
    const float* __restrict__ x,    const float* __restrict__ mask,
    const float* __restrict__ bq,   const float* __restrict__ bv,
    const float* __restrict__ tau,  const unsigned short* __restrict__ wT,
    const float* __restrict__ bias, float* __restrict__ out)
{
    __shared__ unsigned short xs[64 * 384];     // 49152 B, swizzled
    __shared__ unsigned short qk2[2][5120];     // per head: qs[64*40] | ks[64*40]; Ps aliases
    __shared__ unsigned short vT2[2][32 * 72];  // per head: v transposed [d][token]
    __shared__ float qn2[2][64];
    __shared__ float kn2[2][64];

    const int tid  = threadIdx.x;
    const int b    = blockIdx.x;
    const int w    = tid >> 6;        // 0..7
    const int lane = tid & 63;
    const int quad = lane >> 4;
    const int lq   = lane & 15;
    const int mt   = w & 3;           // m-tile (16 rows)
    const int hw   = w >> 2;          // head slot 0..1
    const int t0   = mt * 16 + quad * 4;

    unsigned int* xsu = (unsigned int*)xs;

    // ---- hoist mask tile into registers (head-invariant per wave) ----
    float maskv[4][4];
    #pragma unroll
    for (int nt = 0; nt < 4; ++nt)
        #pragma unroll
        for (int r = 0; r < 4; ++r)
            maskv[nt][r] = mask[(size_t)b * 4096 + (t0 + r) * 64 + nt * 16 + lq];

    // ---- stage x once: 64 tok x 384 k, fp32 -> bf16, swizzled ----
    {
        const int row = tid >> 3;             // 0..63
        const int t8  = tid & 7;              // 0..7
        const float* xr = &x[((size_t)b * NTOK + row) * NC];
        #pragma unroll
        for (int e = 0; e < 12; ++e) {
            const float4 xv = *(const float4*)&xr[(t8 + e * 8) * 4];
            const int p = (t8 + e * 8) * 2;   // uint index within row (unswizzled)
            const int g = p >> 2;
            const int u = row * 192 + (((g ^ (row & 7)) << 2) | (p & 3));
            uint2 w2;
            w2.x = pack2(xv.x, xv.y);
            w2.y = pack2(xv.z, xv.w);
            *(uint2*)&xsu[u] = w2;
        }
    }
    __syncthreads();

    unsigned short* qs_h = qk2[hw];
    unsigned short* ks_h = qk2[hw] + 2560;
    unsigned short* Ps_h = qk2[hw];           // alias (qs/ks dead when P written)
    unsigned short* vT_h = vT2[hw];

    for (int it = 0; it < 6; ++it) {
        const int h = it * 2 + hw;

        // ---------- QKV: this wave computes its head's q|k|v cols for its m-tile ----------
        f32x4 acc[6];
        #pragma unroll
        for (int j = 0; j < 6; ++j) acc[j] = (f32x4){0.f, 0.f, 0.f, 0.f};

        const unsigned short* bp[6];
        #pragma unroll
        for (int j = 0; j < 6; ++j) {
            // j: 0,1 = q halves; 2,3 = k halves; 4,5 = v halves
            const int col = (j >> 1) * 384 + h * 32 + (j & 1) * 16 + lq;
            bp[j] = wT + (size_t)col * NC + quad * 8;
        }

        for (int ksI = 0; ksI < 12; ++ksI) {
            const short8 a = tile_afrag(xs, mt * 16 + lq, ksI * 4 + quad);
            #pragma unroll
            for (int j = 0; j < 6; ++j)
                acc[j] = mfma_bf16(a, *(const short8*)&bp[j][ksI * 32], acc[j]);
        }

        // ---------- prefetch bias for this wave's S tile (hidden by scatter) ----------
        float biasv[4][4];
        #pragma unroll
        for (int nt = 0; nt < 4; ++nt)
            #pragma unroll
            for (int r = 0; r < 4; ++r)
                biasv[nt][r] = bias[h * 4096 + (t0 + r) * 64 + nt * 16 + lq];

        __syncthreads();   // B1 — WAR: prior iteration's PV reads of Ps/vT complete

        // ---------- scatter q/k/v (+biases) with in-register norms ----------
        float qnl[4];
        {
            const float bq0 = bq[h * 32 + lq], bq1 = bq[h * 32 + 16 + lq];
            const float bv0 = bv[h * 32 + lq], bv1 = bv[h * 32 + 16 + lq];

            float qred[4], kred[4];
            #pragma unroll
            for (int r = 0; r < 4; ++r) {
                const float q0 = acc[0][r] + bq0, q1 = acc[1][r] + bq1;
                qs_h[(t0 + r) * 40 + lq]      = f2bf(q0);
                qs_h[(t0 + r) * 40 + 16 + lq] = f2bf(q1);
                ks_h[(t0 + r) * 40 + lq]      = f2bf(acc[2][r]);
                ks_h[(t0 + r) * 40 + 16 + lq] = f2bf(acc[3][r]);
                qred[r] = q0 * q0 + q1 * q1;
                kred[r] = acc[2][r] * acc[2][r] + acc[3][r] * acc[3][r];
            }
            uint2 u2;
            u2.x = pack2(acc[4][0] + bv0, acc[4][1] + bv0);
            u2.y = pack2(acc[4][2] + bv0, acc[4][3] + bv0);
            *(uint2*)&vT_h[lq * 72 + t0] = u2;
            u2.x = pack2(acc[5][0] + bv1, acc[5][1] + bv1);
            u2.y = pack2(acc[5][2] + bv1, acc[5][3] + bv1);
            *(uint2*)&vT_h[(16 + lq) * 72 + t0] = u2;

            // row norms: reduce q0^2+q1^2 (and k) across the 16-lane lq group
            #pragma unroll
            for (int r = 0; r < 4; ++r) {
                #pragma unroll
                for (int off = 1; off < 16; off <<= 1) {
                    qred[r] += __shfl_xor(qred[r], off, 64);
                    kred[r] += __shfl_xor(kred[r], off, 64);
                }
                qnl[r] = sqrtf(qred[r]);
            }
            if (lq == 0) {
                #pragma unroll
                for (int r = 0; r < 4; ++r) {
                    qn2[hw][t0 + r] = qnl[r];
                    kn2[hw][t0 + r] = sqrtf(kred[r]);
                }
            }
        }
        __syncthreads();   // B2

        // ---------- S = q @ kT (wave owns m-tile mt of head h) ----------
        const float ls = fmaxf(tau[h] + 2.302585093f, 0.01f);
        const short8 aq = *(const short8*)&qs_h[(mt * 16 + lq) * 40 + quad * 8];
        float svf[4][4];
        #pragma unroll
        for (int nt = 0; nt < 4; ++nt) {
            const short8 bk = *(const short8*)&ks_h[(nt * 16 + lq) * 40 + quad * 8];
            const f32x4 sv = mfma_bf16(aq, bk, (f32x4){0.f, 0.f, 0.f, 0.f});
            const float knc = kn2[hw][nt * 16 + lq];
            #pragma unroll
            for (int r = 0; r < 4; ++r) {
                const float den = fmaxf(qnl[r] * knc, 1e-6f);
                svf[nt][r] = sv[r] / den * ls + biasv[nt][r] + maskv[nt][r];
            }
        }

        // softmax across the 16-lane lq group (cols live in lq x nt)
        float mx[4], sm[4];
        #pragma unroll
        for (int r = 0; r < 4; ++r) {
            float m = fmaxf(fmaxf(svf[0][r], svf[1][r]), fmaxf(svf[2][r], svf[3][r]));
            #pragma unroll
            for (int off = 1; off < 16; off <<= 1) m = fmaxf(m, __shfl_xor(m, off, 64));
            mx[r] = m; sm[r] = 0.f;
        }
        #pragma unroll
        for (int nt = 0; nt < 4; ++nt)
            #pragma unroll
            for (int r = 0; r < 4; ++r) {
                const float e = __expf(svf[nt][r] - mx[r]);
                svf[nt][r] = e; sm[r] += e;
            }
        #pragma unroll
        for (int r = 0; r < 4; ++r) {
            #pragma unroll
            for (int off = 1; off < 16; off <<= 1) sm[r] += __shfl_xor(sm[r], off, 64);
        }

        __syncthreads();   // B3 — all S reads of qs/ks done before Ps overwrite

        #pragma unroll
        for (int nt = 0; nt < 4; ++nt)
            #pragma unroll
            for (int r = 0; r < 4; ++r)
                Ps_h[(t0 + r) * 72 + nt * 16 + lq] = f2bf(svf[nt][r]);

        // no barrier: PV reads only this wave's own Ps rows (self-visible);
        // vT was synced at B2; WAR vs next scatter is covered by next B1.

        // ---------- O = P @ v (same rows as S phase: sm stays in registers) ----------
        f32x4 oa[2];
        oa[0] = (f32x4){0.f, 0.f, 0.f, 0.f};
        oa[1] = (f32x4){0.f, 0.f, 0.f, 0.f};
        #pragma unroll
        for (int st = 0; st < 2; ++st) {
            const short8 ap = *(const short8*)&Ps_h[(mt * 16 + lq) * 72 + st * 32 + quad * 8];
            #pragma unroll
            for (int n = 0; n < 2; ++n) {
                const short8 bv_ = *(const short8*)&vT_h[(n * 16 + lq) * 72 + st * 32 + quad * 8];
                oa[n] = mfma_bf16(ap, bv_, oa[n]);
            }
        }
        float rsi[4];
        #pragma unroll
        for (int r = 0; r < 4; ++r) rsi[r] = 1.0f / sm[r];
        #pragma unroll
        for (int n = 0; n < 2; ++n)
            #pragma unroll
            for (int r = 0; r < 4; ++r)
                out[((size_t)b * NTOK + t0 + r) * NC + h * 32 + n * 16 + lq] = oa[n][r] * rsi[r];
    }
}

// ---------------------------------------------------------------------------
// proj: out = out @ wproj + bproj, in-place. 1152 blocks x 256.
// Stage 64x384 tile once (swizzled bf16), then 288 MFMAs/wave barrier-free.
// ---------------------------------------------------------------------------
__global__ __launch_bounds__(256) void proj_kernel(
    const unsigned short* __restrict__ wprojT, const float* __restrict__ bproj,
    float* __restrict__ out)
{
    __shared__ unsigned short as_[64 * 384];  // 49152 B, swizzled
    unsigned int* asu = (unsigned int*)as_;

    const int tid  = threadIdx.x;
    const size_t r0 = (size_t)blockIdx.x * 64;
    const int w    = tid >> 6;
    const int lane = tid & 63;
    const int quad = lane >> 4;
    const int lq   = lane & 15;

    {
        const int row = tid >> 2;
        const int q4  = tid & 3;
        const float* xr = &out[(r0 + row) * NC + q4 * 96];
        #pragma unroll
        for (int e = 0; e < 24; ++e) {
            const float4 xv = *(const float4*)&xr[e * 4];
            const int p = q4 * 48 + e * 2;
            const int g = p >> 2;
            const int u = row * 192 + (((g ^ (row & 7)) << 2) | (p & 3));
            uint2 w2;
            w2.x = pack2(xv.x, xv.y);
            w2.y = pack2(xv.z, xv.w);
            *(uint2*)&asu[u] = w2;
        }
    }
    __syncthreads();

    f32x4 acc[4][6];
    #pragma unroll
    for (int mt = 0; mt < 4; ++mt)
        #pragma unroll
        for (int n = 0; n < 6; ++n) acc[mt][n] = (f32x4){0.f, 0.f, 0.f, 0.f};

    const unsigned short* bp[6];
    #pragma unroll
    for (int n = 0; n < 6; ++n)
        bp[n] = wprojT + (size_t)(w * 96 + n * 16 + lq) * NC + quad * 8;

    for (int ksI = 0; ksI < 12; ++ksI) {
        short8 am[4];
        #pragma unroll
        for (int mt = 0; mt < 4; ++mt)
            am[mt] = tile_afrag(as_, mt * 16 + lq, ksI * 4 + quad);
        #pragma unroll
        for (int n = 0; n < 6; ++n) {
            const short8 bb = *(const short8*)&bp[n][ksI * 32];
            #pragma unroll
            for (int mt = 0; mt < 4; ++mt) acc[mt][n] = mfma_bf16(am[mt], bb, acc[mt][n]);
        }
    }

    float bpv[6];
    #pragma unroll
    for (int n = 0; n < 6; ++n) bpv[n] = bproj[w * 96 + n * 16 + lq];
    #pragma unroll
    for (int mt = 0; mt < 4; ++mt)
        #pragma unroll
        for (int n = 0; n < 6; ++n)
            #pragma unroll
            for (int r = 0; r < 4; ++r)
                out[(r0 + mt * 16 + quad * 4 + r) * NC + w * 96 + n * 16 + lq]
                    = acc[mt][n][r] + bpv[n];
}

// ---------------------------------------------------------------------------
extern "C" void kernel_launch(void* const* d_in, const int* in_sizes, int n_in,
                              void* d_out, int out_size, void* d_ws, size_t ws_size,
                              hipStream_t stream) {
    (void)in_sizes; (void)n_in; (void)out_size; (void)ws_size;
    const float* x     = (const float*)d_in[0];
    const float* mask  = (const float*)d_in[1];
    const float* wq    = (const float*)d_in[2];
    const float* bq    = (const float*)d_in[3];
    const float* wk    = (const float*)d_in[4];
    const float* wv    = (const float*)d_in[5];
    const float* bv    = (const float*)d_in[6];
    const float* w1    = (const float*)d_in[7];
    const float* b1    = (const float*)d_in[8];
    const float* w2    = (const float*)d_in[9];
    const float* b2    = (const float*)d_in[10];
    const float* tau   = (const float*)d_in[11];
    const float* wproj = (const float*)d_in[12];
    const float* bproj = (const float*)d_in[13];
    float* out = (float*)d_out;

    // ws: wT 884736 | wprojT 294912 | bias 196608 | tbs 10800  (~1.39 MB)
    unsigned short* wT     = (unsigned short*)d_ws;
    unsigned short* wprojT = (unsigned short*)((char*)d_ws + 884736);
    float*          bias   = (float*)((char*)d_ws + 884736 + 294912);
    float*          tbs    = (float*)((char*)d_ws + 884736 + 294912 + 196608);

    prep_kernel<<<1152, 256, 0, stream>>>(wq, wk, wv, wproj,
                                          (unsigned int*)wT, (unsigned int*)wprojT);
    cpb_mlp_kernel<<<225, 64, 0, stream>>>(w1, b1, w2, b2, tbs);
    bias_gather_kernel<<<48, 1024, 0, stream>>>(tbs, bias);
    attn_kernel<<<NB, 512, 0, stream>>>(x, mask, bq, bv, tau, wT, bias, out);
    proj_kernel<<<NB, 256, 0, stream>>>(wprojT, bproj, out);
}

// Round 3
// 780.885 us; speedup vs baseline: 1.1116x; 1.0916x over previous
//
#include <hip/hip_runtime.h>
#include <math.h>

#define NB   1152
#define NTOK 64
#define NC   384
#define NH   12
#define NDH  32

typedef short short8 __attribute__((ext_vector_type(8)));
typedef float f32x4  __attribute__((ext_vector_type(4)));

__device__ __forceinline__ unsigned short f2bf(float f) {
    unsigned int u = __builtin_bit_cast(unsigned int, f);
    unsigned int r = u + 0x7fffu + ((u >> 16) & 1u);   // RNE
    return (unsigned short)(r >> 16);
}
__device__ __forceinline__ unsigned int pack2(float lo, float hi) {
    return (unsigned int)f2bf(lo) | ((unsigned int)f2bf(hi) << 16);
}
__device__ __forceinline__ f32x4 mfma_bf16(short8 a, short8 b, f32x4 c) {
    return __builtin_amdgcn_mfma_f32_16x16x32_bf16(a, b, c, 0, 0, 0);
}

// XOR-swizzled 64x384 bf16 tile (no padding, 2-way-free bank pattern).
__device__ __forceinline__ short8 tile_afrag(const unsigned short* t, int row, int kq) {
    return *(const short8*)((const char*)t + row * 768 + ((kq ^ (row & 7)) << 4));
}

// Repack transposed-QKV accumulators into an MFMA A/B fragment.
// Inputs: a0 = acc for dh 0..15 of this tile (lane holds dh 4*Q+r, tok t),
//         a1 = acc for dh 16..31. Output: lane (Q,t) holds
//         [tok t][dh 8Q..8Q+7] as bf16x8 (the S-phase fragment layout).
__device__ __forceinline__ short8 repack_frag(f32x4 a0, f32x4 a1, int Q, int t) {
    unsigned p00 = pack2(a0[0], a0[1]);   // dh +0,+1  (low 16-dh half)
    unsigned p01 = pack2(a0[2], a0[3]);   // dh +2,+3
    unsigned p10 = pack2(a1[0], a1[1]);   // dh +0,+1  (high 16-dh half)
    unsigned p11 = pack2(a1[2], a1[3]);   // dh +2,+3
    const int s0 = ((Q & 1) << 5) + t;    // src lane: quad 2*(Q&1), same t
    const int s1 = s0 + 16;               // src lane: quad 2*(Q&1)+1
    int u0a = __shfl((int)p00, s0, 64), u0b = __shfl((int)p10, s0, 64);
    int u1a = __shfl((int)p01, s0, 64), u1b = __shfl((int)p11, s0, 64);
    int u2a = __shfl((int)p00, s1, 64), u2b = __shfl((int)p10, s1, 64);
    int u3a = __shfl((int)p01, s1, 64), u3b = __shfl((int)p11, s1, 64);
    const bool hi = (Q & 2) != 0;         // dh-half selected by target quad
    uint4 u;
    u.x = (unsigned)(hi ? u0b : u0a);
    u.y = (unsigned)(hi ? u1b : u1a);
    u.z = (unsigned)(hi ? u2b : u2a);
    u.w = (unsigned)(hi ? u3b : u3a);
    return __builtin_bit_cast(short8, u);
}

// ---------------------------------------------------------------------------
// prep: transpose+convert weights to bf16 col-major (B-operand layout).
// ---------------------------------------------------------------------------
__global__ __launch_bounds__(256) void prep_kernel(
    const float* __restrict__ wq, const float* __restrict__ wk,
    const float* __restrict__ wv, const float* __restrict__ wproj,
    unsigned int* __restrict__ wT, unsigned int* __restrict__ wprojT)
{
    const int o2 = blockIdx.x * 256 + threadIdx.x;
    if (o2 < 221184) {
        const int col = o2 / 192, k2 = o2 % 192, k = k2 * 2;
        const float* src = (col < 384) ? wq : ((col < 768) ? wk : wv);
        const int c = (col < 384) ? col : ((col < 768) ? col - 384 : col - 768);
        const float a = src[(size_t)k * NC + c];
        const float b = src[(size_t)(k + 1) * NC + c];
        wT[col * 192 + k2] = pack2(a, b);
    } else {
        const int o = o2 - 221184;
        const int col = o / 192, k2 = o % 192, k = k2 * 2;
        const float a = wproj[(size_t)k * NC + col];
        const float b = wproj[(size_t)(k + 1) * NC + col];
        wprojT[col * 192 + k2] = pack2(a, b);
    }
}

// ---------------------------------------------------------------------------
// cpb MLP: 225 blocks x 1 wave.
// ---------------------------------------------------------------------------
__global__ __launch_bounds__(64) void cpb_mlp_kernel(
    const float* __restrict__ w1, const float* __restrict__ b1,
    const float* __restrict__ w2, const float* __restrict__ b2,
    float* __restrict__ tbs)
{
    const int p = blockIdx.x;
    const int lane = threadIdx.x;
    const int ip = p / 15, jp = p % 15;
    float u0 = (float)(jp - 7) * (8.0f / 7.0f);
    float u1 = (float)(ip - 7) * (8.0f / 7.0f);
    float s0 = (u0 > 0.f) ? 1.f : ((u0 < 0.f) ? -1.f : 0.f);
    float s1 = (u1 > 0.f) ? 1.f : ((u1 < 0.f) ? -1.f : 0.f);
    float in0 = s0 * log2f(fabsf(u0) + 1.0f) * (1.0f / 3.0f);
    float in1 = s1 * log2f(fabsf(u1) + 1.0f) * (1.0f / 3.0f);

    float a[12];
    #pragma unroll
    for (int m = 0; m < 12; ++m) a[m] = 0.f;
    #pragma unroll
    for (int e = 0; e < 8; ++e) {
        const int j = lane * 8 + e;
        float hh = fmaxf(in0 * w1[j] + in1 * w1[512 + j] + b1[j], 0.0f);
        #pragma unroll
        for (int m = 0; m < 12; ++m) a[m] += hh * w2[j * 12 + m];
    }
    #pragma unroll
    for (int m = 0; m < 12; ++m) {
        #pragma unroll
        for (int off = 1; off < 64; off <<= 1) a[m] += __shfl_xor(a[m], off, 64);
    }
    if (lane < 12) tbs[p * 12 + lane] = a[lane] + b2[lane];
}

__global__ __launch_bounds__(1024) void bias_gather_kernel(
    const float* __restrict__ tbs, float* __restrict__ bias)
{
    const int i = blockIdx.x * 1024 + threadIdx.x;
    if (i >= NH * NTOK * NTOK) return;
    const int h = i >> 12, rem = i & 4095;
    const int ti = rem >> 6, tj = rem & 63;
    const int dr = (ti >> 3) - (tj >> 3);
    const int dc = (ti & 7) - (tj & 7);
    const int p = (dr + 7) * 15 + (dc + 7);
    bias[i] = 16.0f / (1.0f + __expf(-tbs[p * 12 + h]));
}

// ---------------------------------------------------------------------------
// attn: ONE WAVE = ONE HEAD, barrier-free after the x-tile stage.
// 1152 blocks x 256 threads (4 waves). Wave w owns heads 3w..3w+2.
// Per head: transposed-output QKV (C^T: lane holds 4 consecutive dh of one
// token) -> in-register norms + bias, vT scatter to wave-private LDS,
// shfl-repack q/k into S fragments (no qs/ks LDS), then per m-tile:
// S MFMA -> softmax (16-lane groups) -> Ps (wave-private LDS) -> PV -> out.
// Exactly ONE __syncthreads (after xs stage). LDS 75 KiB -> 2 blocks/CU.
// ---------------------------------------------------------------------------
__global__ __launch_bounds__(256, 2) void attn_kernel(
    const float* __restrict__ x,    const float* __restrict__ mask,
    const float* __restrict__ bq,   const float* __restrict__ bv,
    const float* __restrict__ tau,  const unsigned short* __restrict__ wT,
    const float* __restrict__ bias, float* __restrict__ out)
{
    __shared__ unsigned short xs[64 * 384];      // 49152 B, swizzled, shared
    __shared__ unsigned short vTs[4][32 * 72];   // 18432 B, wave-private slices
    __shared__ unsigned short Pss[4][16 * 72];   //  9216 B, wave-private slices

    const int tid = threadIdx.x;
    const int b   = blockIdx.x;
    const int w   = tid >> 6;       // wave 0..3
    const int lane = tid & 63;
    const int Q   = lane >> 4;      // quad 0..3
    const int t   = lane & 15;      // 0..15

    unsigned int* xsu = (unsigned int*)xs;

    // ---- stage x once: 64 tok x 384 k, fp32 -> bf16, swizzled ----
    {
        const int row = tid >> 2;             // 0..63
        const int q4  = tid & 3;              // 0..3
        const float* xr = &x[((size_t)b * NTOK + row) * NC + q4 * 96];
        #pragma unroll
        for (int e = 0; e < 24; ++e) {
            const float4 xv = *(const float4*)&xr[e * 4];
            const int p = q4 * 48 + e * 2;
            const int g = p >> 2;
            const int u = row * 192 + (((g ^ (row & 7)) << 2) | (p & 3));
            uint2 w2;
            w2.x = pack2(xv.x, xv.y);
            w2.y = pack2(xv.z, xv.w);
            *(uint2*)&xsu[u] = w2;
        }
    }
    __syncthreads();   // the ONLY barrier

    unsigned short* vT = vTs[w];
    unsigned short* Ps = Pss[w];

    for (int c = 0; c < 3; ++c) {
        const int h = w * 3 + c;

        // ---------- QKV, transposed output: accT[oc][tt] ----------
        // oc 0,1 = q dh-halves; 2,3 = k; 4,5 = v.  tt = token tile 0..3.
        // Lane (Q,t) of accT[oc][tt] holds value[tok tt*16+t][dh (oc&1)*16+4Q+r].
        f32x4 accT[6][4];
        #pragma unroll
        for (int oc = 0; oc < 6; ++oc)
            #pragma unroll
            for (int tt = 0; tt < 4; ++tt) accT[oc][tt] = (f32x4){0.f, 0.f, 0.f, 0.f};

        const unsigned short* ap[6];
        #pragma unroll
        for (int oc = 0; oc < 6; ++oc) {
            const int cbase = (oc >> 1) * 384 + h * 32 + (oc & 1) * 16;
            ap[oc] = wT + (size_t)(cbase + t) * NC + Q * 8;
        }

        for (int ks = 0; ks < 12; ++ks) {
            short8 bfr[4];
            #pragma unroll
            for (int tt = 0; tt < 4; ++tt)
                bfr[tt] = tile_afrag(xs, tt * 16 + t, ks * 4 + Q);
            #pragma unroll
            for (int oc = 0; oc < 6; ++oc) {
                const short8 af = *(const short8*)&ap[oc][ks * 32];
                #pragma unroll
                for (int tt = 0; tt < 4; ++tt)
                    accT[oc][tt] = mfma_bf16(af, bfr[tt], accT[oc][tt]);
            }
        }

        // ---------- add biases (q, v) in place ----------
        #pragma unroll
        for (int a = 0; a < 2; ++a) {
            #pragma unroll
            for (int r = 0; r < 4; ++r) {
                const float bqv = bq[h * 32 + a * 16 + Q * 4 + r];
                const float bvv = bv[h * 32 + a * 16 + Q * 4 + r];
                #pragma unroll
                for (int tt = 0; tt < 4; ++tt) {
                    accT[a][tt][r]     += bqv;
                    accT[4 + a][tt][r] += bvv;
                }
            }
        }

        // ---------- vT scatter (wave-private, no barrier) ----------
        #pragma unroll
        for (int a = 0; a < 2; ++a)
            #pragma unroll
            for (int tt = 0; tt < 4; ++tt)
                #pragma unroll
                for (int r = 0; r < 4; ++r)
                    vT[(a * 16 + Q * 4 + r) * 72 + tt * 16 + t] = f2bf(accT[4 + a][tt][r]);

        // ---------- norms (in-register; cross-quad shfl reduce) ----------
        float qn[4], kn[4];
        #pragma unroll
        for (int tt = 0; tt < 4; ++tt) {
            float sq = 0.f, sk = 0.f;
            #pragma unroll
            for (int a = 0; a < 2; ++a)
                #pragma unroll
                for (int r = 0; r < 4; ++r) {
                    sq += accT[a][tt][r] * accT[a][tt][r];
                    sk += accT[2 + a][tt][r] * accT[2 + a][tt][r];
                }
            sq += __shfl_xor(sq, 16, 64);  sq += __shfl_xor(sq, 32, 64);
            sk += __shfl_xor(sk, 16, 64);  sk += __shfl_xor(sk, 32, 64);
            qn[tt] = sqrtf(sq);
            kn[tt] = sqrtf(sk);
        }

        // ---------- k fragments for S (shfl repack; k-accs die here) ----------
        short8 bk[4];
        #pragma unroll
        for (int nt = 0; nt < 4; ++nt)
            bk[nt] = repack_frag(accT[2][nt], accT[3][nt], Q, t);

        // ---------- v fragments for PV (from wave-private vT) ----------
        short8 vf[2][2];
        #pragma unroll
        for (int n = 0; n < 2; ++n)
            #pragma unroll
            for (int st = 0; st < 2; ++st)
                vf[n][st] = *(const short8*)&vT[(n * 16 + t) * 72 + st * 32 + Q * 8];

        const float ls = fmaxf(tau[h] + 2.302585093f, 0.01f);

        // ---------- per m-tile: S -> softmax -> Ps -> PV -> out ----------
        #pragma unroll
        for (int mt = 0; mt < 4; ++mt) {
            // bias+mask for this tile (independent loads, issued early)
            float bmv[4][4];
            #pragma unroll
            for (int nt = 0; nt < 4; ++nt)
                #pragma unroll
                for (int r = 0; r < 4; ++r) {
                    const int row = mt * 16 + Q * 4 + r;
                    const int col = nt * 16 + t;
                    bmv[nt][r] = bias[h * 4096 + row * 64 + col]
                               + mask[(size_t)b * 4096 + row * 64 + col];
                }

            const short8 aq = repack_frag(accT[0][mt], accT[1][mt], Q, t);
            float qr[4];
            #pragma unroll
            for (int r = 0; r < 4; ++r) qr[r] = __shfl(qn[mt], Q * 4 + r, 64);

            float svf[4][4];
            #pragma unroll
            for (int nt = 0; nt < 4; ++nt) {
                const f32x4 sv = mfma_bf16(aq, bk[nt], (f32x4){0.f, 0.f, 0.f, 0.f});
                #pragma unroll
                for (int r = 0; r < 4; ++r) {
                    const float den = fmaxf(qr[r] * kn[nt], 1e-6f);
                    svf[nt][r] = sv[r] / den * ls + bmv[nt][r];
                }
            }

            // softmax across the 16-lane group (row = Q*4+r fixed per lane)
            float mx[4], sm[4];
            #pragma unroll
            for (int r = 0; r < 4; ++r) {
                float m = fmaxf(fmaxf(svf[0][r], svf[1][r]), fmaxf(svf[2][r], svf[3][r]));
                #pragma unroll
                for (int off = 1; off < 16; off <<= 1) m = fmaxf(m, __shfl_xor(m, off, 64));
                mx[r] = m; sm[r] = 0.f;
            }
            #pragma unroll
            for (int nt = 0; nt < 4; ++nt)
                #pragma unroll
                for (int r = 0; r < 4; ++r) {
                    const float e = __expf(svf[nt][r] - mx[r]);
                    svf[nt][r] = e; sm[r] += e;
                }
            #pragma unroll
            for (int r = 0; r < 4; ++r) {
                #pragma unroll
                for (int off = 1; off < 16; off <<= 1) sm[r] += __shfl_xor(sm[r], off, 64);
            }

            // Ps write (wave-private; visible after lgkmcnt, no barrier)
            #pragma unroll
            for (int nt = 0; nt < 4; ++nt)
                #pragma unroll
                for (int r = 0; r < 4; ++r)
                    Ps[(Q * 4 + r) * 72 + nt * 16 + t] = f2bf(svf[nt][r]);

            // PV
            f32x4 oa[2];
            oa[0] = (f32x4){0.f, 0.f, 0.f, 0.f};
            oa[1] = (f32x4){0.f, 0.f, 0.f, 0.f};
            #pragma unroll
            for (int st = 0; st < 2; ++st) {
                const short8 apf = *(const short8*)&Ps[t * 72 + st * 32 + Q * 8];
                #pragma unroll
                for (int n = 0; n < 2; ++n)
                    oa[n] = mfma_bf16(apf, vf[n][st], oa[n]);
            }

            float rsi[4];
            #pragma unroll
            for (int r = 0; r < 4; ++r) rsi[r] = 1.0f / sm[r];
            #pragma unroll
            for (int n = 0; n < 2; ++n)
                #pragma unroll
                for (int r = 0; r < 4; ++r)
                    out[((size_t)b * NTOK + mt * 16 + Q * 4 + r) * NC + h * 32 + n * 16 + t]
                        = oa[n][r] * rsi[r];
        }
    }
}

// ---------------------------------------------------------------------------
// proj: out = out @ wproj + bproj, in-place. 1152 blocks x 256. (unchanged)
// ---------------------------------------------------------------------------
__global__ __launch_bounds__(256) void proj_kernel(
    const unsigned short* __restrict__ wprojT, const float* __restrict__ bproj,
    float* __restrict__ out)
{
    __shared__ unsigned short as_[64 * 384];
    unsigned int* asu = (unsigned int*)as_;

    const int tid  = threadIdx.x;
    const size_t r0 = (size_t)blockIdx.x * 64;
    const int w    = tid >> 6;
    const int lane = tid & 63;
    const int quad = lane >> 4;
    const int lq   = lane & 15;

    {
        const int row = tid >> 2;
        const int q4  = tid & 3;
        const float* xr = &out[(r0 + row) * NC + q4 * 96];
        #pragma unroll
        for (int e = 0; e < 24; ++e) {
            const float4 xv = *(const float4*)&xr[e * 4];
            const int p = q4 * 48 + e * 2;
            const int g = p >> 2;
            const int u = row * 192 + (((g ^ (row & 7)) << 2) | (p & 3));
            uint2 w2;
            w2.x = pack2(xv.x, xv.y);
            w2.y = pack2(xv.z, xv.w);
            *(uint2*)&asu[u] = w2;
        }
    }
    __syncthreads();

    f32x4 acc[4][6];
    #pragma unroll
    for (int mt = 0; mt < 4; ++mt)
        #pragma unroll
        for (int n = 0; n < 6; ++n) acc[mt][n] = (f32x4){0.f, 0.f, 0.f, 0.f};

    const unsigned short* bp[6];
    #pragma unroll
    for (int n = 0; n < 6; ++n)
        bp[n] = wprojT + (size_t)(w * 96 + n * 16 + lq) * NC + quad * 8;

    for (int ksI = 0; ksI < 12; ++ksI) {
        short8 am[4];
        #pragma unroll
        for (int mt = 0; mt < 4; ++mt)
            am[mt] = tile_afrag(as_, mt * 16 + lq, ksI * 4 + quad);
        #pragma unroll
        for (int n = 0; n < 6; ++n) {
            const short8 bb = *(const short8*)&bp[n][ksI * 32];
            #pragma unroll
            for (int mt = 0; mt < 4; ++mt) acc[mt][n] = mfma_bf16(am[mt], bb, acc[mt][n]);
        }
    }

    float bpv[6];
    #pragma unroll
    for (int n = 0; n < 6; ++n) bpv[n] = bproj[w * 96 + n * 16 + lq];
    #pragma unroll
    for (int mt = 0; mt < 4; ++mt)
        #pragma unroll
        for (int n = 0; n < 6; ++n)
            #pragma unroll
            for (int r = 0; r < 4; ++r)
                out[(r0 + mt * 16 + quad * 4 + r) * NC + w * 96 + n * 16 + lq]
                    = acc[mt][n][r] + bpv[n];
}

// ---------------------------------------------------------------------------
extern "C" void kernel_launch(void* const* d_in, const int* in_sizes, int n_in,
                              void* d_out, int out_size, void* d_ws, size_t ws_size,
                              hipStream_t stream) {
    (void)in_sizes; (void)n_in; (void)out_size; (void)ws_size;
    const float* x     = (const float*)d_in[0];
    const float* mask  = (const float*)d_in[1];
    const float* wq    = (const float*)d_in[2];
    const float* bq    = (const float*)d_in[3];
    const float* wk    = (const float*)d_in[4];
    const float* wv    = (const float*)d_in[5];
    const float* bv    = (const float*)d_in[6];
    const float* w1    = (const float*)d_in[7];
    const float* b1    = (const float*)d_in[8];
    const float* w2    = (const float*)d_in[9];
    const float* b2    = (const float*)d_in[10];
    const float* tau   = (const float*)d_in[11];
    const float* wproj = (const float*)d_in[12];
    const float* bproj = (const float*)d_in[13];
    float* out = (float*)d_out;

    // ws: wT 884736 | wprojT 294912 | bias 196608 | tbs 10800  (~1.39 MB)
    unsigned short* wT     = (unsigned short*)d_ws;
    unsigned short* wprojT = (unsigned short*)((char*)d_ws + 884736);
    float*          bias   = (float*)((char*)d_ws + 884736 + 294912);
    float*          tbs    = (float*)((char*)d_ws + 884736 + 294912 + 196608);

    prep_kernel<<<1152, 256, 0, stream>>>(wq, wk, wv, wproj,
                                          (unsigned int*)wT, (unsigned int*)wprojT);
    cpb_mlp_kernel<<<225, 64, 0, stream>>>(w1, b1, w2, b2, tbs);
    bias_gather_kernel<<<48, 1024, 0, stream>>>(tbs, bias);
    attn_kernel<<<NB, 256, 0, stream>>>(x, mask, bq, bv, tau, wT, bias, out);
    proj_kernel<<<NB, 256, 0, stream>>>(wprojT, bproj, out);
}

// Round 4
// 631.442 us; speedup vs baseline: 1.3747x; 1.2367x over previous
//
#include <hip/hip_runtime.h>
#include <math.h>

#define NB   1152
#define NTOK 64
#define NC   384
#define NH   12
#define NDH  32

typedef short short8 __attribute__((ext_vector_type(8)));
typedef float f32x4  __attribute__((ext_vector_type(4)));

__device__ __forceinline__ unsigned short f2bf(float f) {
    unsigned int u = __builtin_bit_cast(unsigned int, f);
    unsigned int r = u + 0x7fffu + ((u >> 16) & 1u);   // RNE
    return (unsigned short)(r >> 16);
}
__device__ __forceinline__ unsigned int pack2(float lo, float hi) {
    return (unsigned int)f2bf(lo) | ((unsigned int)f2bf(hi) << 16);
}
__device__ __forceinline__ f32x4 mfma_bf16(short8 a, short8 b, f32x4 c) {
    return __builtin_amdgcn_mfma_f32_16x16x32_bf16(a, b, c, 0, 0, 0);
}

// XOR-swizzled 64x384 bf16 tile (no padding, 2-way-free bank pattern).
__device__ __forceinline__ short8 tile_afrag(const unsigned short* t, int row, int kq) {
    return *(const short8*)((const char*)t + row * 768 + ((kq ^ (row & 7)) << 4));
}

// Repack transposed-QKV accumulators into an MFMA A/B fragment.
// Inputs: a0 = acc for dh 0..15 of this tile (lane holds dh 4*Q+r, tok t),
//         a1 = acc for dh 16..31. Output: lane (Q,t) holds
//         [tok t][dh 8Q..8Q+7] as bf16x8 (the S-phase fragment layout).
__device__ __forceinline__ short8 repack_frag(f32x4 a0, f32x4 a1, int Q, int t) {
    unsigned p00 = pack2(a0[0], a0[1]);
    unsigned p01 = pack2(a0[2], a0[3]);
    unsigned p10 = pack2(a1[0], a1[1]);
    unsigned p11 = pack2(a1[2], a1[3]);
    const int s0 = ((Q & 1) << 5) + t;
    const int s1 = s0 + 16;
    int u0a = __shfl((int)p00, s0, 64), u0b = __shfl((int)p10, s0, 64);
    int u1a = __shfl((int)p01, s0, 64), u1b = __shfl((int)p11, s0, 64);
    int u2a = __shfl((int)p00, s1, 64), u2b = __shfl((int)p10, s1, 64);
    int u3a = __shfl((int)p01, s1, 64), u3b = __shfl((int)p11, s1, 64);
    const bool hi = (Q & 2) != 0;
    uint4 u;
    u.x = (unsigned)(hi ? u0b : u0a);
    u.y = (unsigned)(hi ? u1b : u1a);
    u.z = (unsigned)(hi ? u2b : u2a);
    u.w = (unsigned)(hi ? u3b : u3a);
    return __builtin_bit_cast(short8, u);
}

// ---------------------------------------------------------------------------
// prep: transpose+convert weights to bf16 col-major (B-operand layout).
// ---------------------------------------------------------------------------
__global__ __launch_bounds__(256) void prep_kernel(
    const float* __restrict__ wq, const float* __restrict__ wk,
    const float* __restrict__ wv, const float* __restrict__ wproj,
    unsigned int* __restrict__ wT, unsigned int* __restrict__ wprojT)
{
    const int o2 = blockIdx.x * 256 + threadIdx.x;
    if (o2 < 221184) {
        const int col = o2 / 192, k2 = o2 % 192, k = k2 * 2;
        const float* src = (col < 384) ? wq : ((col < 768) ? wk : wv);
        const int c = (col < 384) ? col : ((col < 768) ? col - 384 : col - 768);
        const float a = src[(size_t)k * NC + c];
        const float b = src[(size_t)(k + 1) * NC + c];
        wT[col * 192 + k2] = pack2(a, b);
    } else {
        const int o = o2 - 221184;
        const int col = o / 192, k2 = o % 192, k = k2 * 2;
        const float a = wproj[(size_t)k * NC + col];
        const float b = wproj[(size_t)(k + 1) * NC + col];
        wprojT[col * 192 + k2] = pack2(a, b);
    }
}

// ---------------------------------------------------------------------------
// cpb MLP: 225 blocks x 1 wave.
// ---------------------------------------------------------------------------
__global__ __launch_bounds__(64) void cpb_mlp_kernel(
    const float* __restrict__ w1, const float* __restrict__ b1,
    const float* __restrict__ w2, const float* __restrict__ b2,
    float* __restrict__ tbs)
{
    const int p = blockIdx.x;
    const int lane = threadIdx.x;
    const int ip = p / 15, jp = p % 15;
    float u0 = (float)(jp - 7) * (8.0f / 7.0f);
    float u1 = (float)(ip - 7) * (8.0f / 7.0f);
    float s0 = (u0 > 0.f) ? 1.f : ((u0 < 0.f) ? -1.f : 0.f);
    float s1 = (u1 > 0.f) ? 1.f : ((u1 < 0.f) ? -1.f : 0.f);
    float in0 = s0 * log2f(fabsf(u0) + 1.0f) * (1.0f / 3.0f);
    float in1 = s1 * log2f(fabsf(u1) + 1.0f) * (1.0f / 3.0f);

    float a[12];
    #pragma unroll
    for (int m = 0; m < 12; ++m) a[m] = 0.f;
    #pragma unroll
    for (int e = 0; e < 8; ++e) {
        const int j = lane * 8 + e;
        float hh = fmaxf(in0 * w1[j] + in1 * w1[512 + j] + b1[j], 0.0f);
        #pragma unroll
        for (int m = 0; m < 12; ++m) a[m] += hh * w2[j * 12 + m];
    }
    #pragma unroll
    for (int m = 0; m < 12; ++m) {
        #pragma unroll
        for (int off = 1; off < 64; off <<= 1) a[m] += __shfl_xor(a[m], off, 64);
    }
    if (lane < 12) tbs[p * 12 + lane] = a[lane] + b2[lane];
}

__global__ __launch_bounds__(1024) void bias_gather_kernel(
    const float* __restrict__ tbs, float* __restrict__ bias)
{
    const int i = blockIdx.x * 1024 + threadIdx.x;
    if (i >= NH * NTOK * NTOK) return;
    const int h = i >> 12, rem = i & 4095;
    const int ti = rem >> 6, tj = rem & 63;
    const int dr = (ti >> 3) - (tj >> 3);
    const int dc = (ti & 7) - (tj & 7);
    const int p = (dr + 7) * 15 + (dc + 7);
    bias[i] = 16.0f / (1.0f + __expf(-tbs[p * 12 + h]));
}

// ---------------------------------------------------------------------------
// attn: ONE WAVE = ONE HEAD, barrier-free after the x-tile stage.
// 1152 blocks x 256 threads (4 waves). Wave w owns heads 3w..3w+2.
// TWO-PASS QKV to keep peak live regs < 128 (R3's one-pass accT[6][4]=96
// acc regs spilled ~100MB of scratch traffic to HBM):
//   pass1 K+V (acckv[4][4]=64 regs) -> bk frags + kn + vT LDS, accs die;
//   pass2 Q   (accq[2][4]=32 regs)  -> aqf frags + qn, accs die.
// Mask hoisted to registers once per block (head-invariant).
// Exactly ONE __syncthreads. LDS 75 KiB -> 2 blocks/CU.
// ---------------------------------------------------------------------------
__global__ __launch_bounds__(256, 2) void attn_kernel(
    const float* __restrict__ x,    const float* __restrict__ mask,
    const float* __restrict__ bq,   const float* __restrict__ bv,
    const float* __restrict__ tau,  const unsigned short* __restrict__ wT,
    const float* __restrict__ bias, float* __restrict__ out)
{
    __shared__ unsigned short xs[64 * 384];      // 49152 B, swizzled, shared
    __shared__ unsigned short vTs[4][32 * 72];   // 18432 B, wave-private slices
    __shared__ unsigned short Pss[4][16 * 72];   //  9216 B, wave-private slices

    const int tid = threadIdx.x;
    const int b   = blockIdx.x;
    const int w   = tid >> 6;       // wave 0..3
    const int lane = tid & 63;
    const int Q   = lane >> 4;      // quad 0..3
    const int t   = lane & 15;      // 0..15

    unsigned int* xsu = (unsigned int*)xs;

    // ---- hoist mask into registers (head-invariant; lane owns its S cells) ----
    float maskv[4][4];
    #pragma unroll
    for (int nt = 0; nt < 4; ++nt)
        #pragma unroll
        for (int r = 0; r < 4; ++r)
            maskv[nt][r] = mask[(size_t)b * 4096 + (Q * 4 + r) * 64 + nt * 16 + t];
    // NOTE: maskv[nt][r] above is for m-tile 0 rows; rows repeat per m-tile as
    // (mt*16 + Q*4 + r). mask depends on full row, so load per m-tile set:
    // mask[b][row][col] with row = mt*16+Q*4+r. We need all 4 m-tiles ->
    // keep 4x4 per m-tile is 64 regs (too many). Instead exploit that the
    // row pattern within a window mask repeats only if mask is block-constant;
    // it is NOT in general. So: load per m-tile inside the loop, but only ONCE
    // per block (not per head) into LDS? Simplest correct+cheap: keep per-head
    // reload of mask folded into bias load below (L2-resident). maskv unused.
    (void)maskv;

    // ---- stage x once: 64 tok x 384 k, fp32 -> bf16, swizzled ----
    {
        const int row = tid >> 2;             // 0..63
        const int q4  = tid & 3;              // 0..3
        const float* xr = &x[((size_t)b * NTOK + row) * NC + q4 * 96];
        #pragma unroll
        for (int e = 0; e < 24; ++e) {
            const float4 xv = *(const float4*)&xr[e * 4];
            const int p = q4 * 48 + e * 2;
            const int g = p >> 2;
            const int u = row * 192 + (((g ^ (row & 7)) << 2) | (p & 3));
            uint2 w2;
            w2.x = pack2(xv.x, xv.y);
            w2.y = pack2(xv.z, xv.w);
            *(uint2*)&xsu[u] = w2;
        }
    }
    __syncthreads();   // the ONLY barrier

    unsigned short* vT = vTs[w];
    unsigned short* Ps = Pss[w];

    for (int c = 0; c < 3; ++c) {
        const int h = w * 3 + c;

        // ================= PASS 1: K and V =================
        // acckv: 0,1 = k dh-halves; 2,3 = v dh-halves. Lane (Q,t) of
        // acckv[j][tt] holds val[tok tt*16+t][dh (j&1)*16+4Q+r].
        f32x4 acckv[4][4];
        #pragma unroll
        for (int j = 0; j < 4; ++j)
            #pragma unroll
            for (int tt = 0; tt < 4; ++tt) acckv[j][tt] = (f32x4){0.f, 0.f, 0.f, 0.f};

        {
            const unsigned short* ap[4];
            #pragma unroll
            for (int j = 0; j < 4; ++j) {
                const int cbase = (1 + (j >> 1)) * 384 + h * 32 + (j & 1) * 16; // k then v
                ap[j] = wT + (size_t)(cbase + t) * NC + Q * 8;
            }
            for (int ks = 0; ks < 12; ++ks) {
                short8 bfr[4];
                #pragma unroll
                for (int tt = 0; tt < 4; ++tt)
                    bfr[tt] = tile_afrag(xs, tt * 16 + t, ks * 4 + Q);
                #pragma unroll
                for (int j = 0; j < 4; ++j) {
                    const short8 af = *(const short8*)&ap[j][ks * 32];
                    #pragma unroll
                    for (int tt = 0; tt < 4; ++tt)
                        acckv[j][tt] = mfma_bf16(af, bfr[tt], acckv[j][tt]);
                }
            }
        }

        // ---- v bias + vT scatter (wave-private) ----
        #pragma unroll
        for (int a = 0; a < 2; ++a) {
            #pragma unroll
            for (int r = 0; r < 4; ++r) {
                const float bvv = bv[h * 32 + a * 16 + Q * 4 + r];
                #pragma unroll
                for (int tt = 0; tt < 4; ++tt)
                    vT[(a * 16 + Q * 4 + r) * 72 + tt * 16 + t]
                        = f2bf(acckv[2 + a][tt][r] + bvv);
            }
        }

        // ---- k norms (no bias on k) ----
        float kn[4];
        #pragma unroll
        for (int tt = 0; tt < 4; ++tt) {
            float sk = 0.f;
            #pragma unroll
            for (int a = 0; a < 2; ++a)
                #pragma unroll
                for (int r = 0; r < 4; ++r)
                    sk += acckv[a][tt][r] * acckv[a][tt][r];
            sk += __shfl_xor(sk, 16, 64);
            sk += __shfl_xor(sk, 32, 64);
            kn[tt] = sqrtf(sk);
        }

        // ---- k fragments for S (k accs die here) ----
        short8 bk[4];
        #pragma unroll
        for (int nt = 0; nt < 4; ++nt)
            bk[nt] = repack_frag(acckv[0][nt], acckv[1][nt], Q, t);

        // ---- v fragments for PV (reads this wave's vT; overlaps pass 2) ----
        short8 vf[2][2];
        #pragma unroll
        for (int n = 0; n < 2; ++n)
            #pragma unroll
            for (int st = 0; st < 2; ++st)
                vf[n][st] = *(const short8*)&vT[(n * 16 + t) * 72 + st * 32 + Q * 8];

        // ================= PASS 2: Q =================
        f32x4 accq[2][4];
        #pragma unroll
        for (int a = 0; a < 2; ++a)
            #pragma unroll
            for (int tt = 0; tt < 4; ++tt) accq[a][tt] = (f32x4){0.f, 0.f, 0.f, 0.f};

        {
            const unsigned short* ap[2];
            #pragma unroll
            for (int a = 0; a < 2; ++a)
                ap[a] = wT + (size_t)(h * 32 + a * 16 + t) * NC + Q * 8;
            for (int ks = 0; ks < 12; ++ks) {
                short8 bfr[4];
                #pragma unroll
                for (int tt = 0; tt < 4; ++tt)
                    bfr[tt] = tile_afrag(xs, tt * 16 + t, ks * 4 + Q);
                #pragma unroll
                for (int a = 0; a < 2; ++a) {
                    const short8 af = *(const short8*)&ap[a][ks * 32];
                    #pragma unroll
                    for (int tt = 0; tt < 4; ++tt)
                        accq[a][tt] = mfma_bf16(af, bfr[tt], accq[a][tt]);
                }
            }
        }

        // ---- q bias, norms, fragments (q accs die here) ----
        float qn[4];
        short8 aqf[4];
        #pragma unroll
        for (int a = 0; a < 2; ++a) {
            #pragma unroll
            for (int r = 0; r < 4; ++r) {
                const float bqv = bq[h * 32 + a * 16 + Q * 4 + r];
                #pragma unroll
                for (int tt = 0; tt < 4; ++tt) accq[a][tt][r] += bqv;
            }
        }
        #pragma unroll
        for (int tt = 0; tt < 4; ++tt) {
            float sq = 0.f;
            #pragma unroll
            for (int a = 0; a < 2; ++a)
                #pragma unroll
                for (int r = 0; r < 4; ++r)
                    sq += accq[a][tt][r] * accq[a][tt][r];
            sq += __shfl_xor(sq, 16, 64);
            sq += __shfl_xor(sq, 32, 64);
            qn[tt] = sqrtf(sq);
            aqf[tt] = repack_frag(accq[0][tt], accq[1][tt], Q, t);
        }

        const float ls = fmaxf(tau[h] + 2.302585093f, 0.01f);

        // ---------- per m-tile: S -> softmax -> Ps -> PV -> out ----------
        #pragma unroll
        for (int mt = 0; mt < 4; ++mt) {
            // bias+mask for this tile (independent loads, issued early)
            float bmv[4][4];
            #pragma unroll
            for (int nt = 0; nt < 4; ++nt)
                #pragma unroll
                for (int r = 0; r < 4; ++r) {
                    const int row = mt * 16 + Q * 4 + r;
                    const int col = nt * 16 + t;
                    bmv[nt][r] = bias[h * 4096 + row * 64 + col]
                               + mask[(size_t)b * 4096 + row * 64 + col];
                }

            float qr[4];
            #pragma unroll
            for (int r = 0; r < 4; ++r) qr[r] = __shfl(qn[mt], Q * 4 + r, 64);

            float svf[4][4];
            #pragma unroll
            for (int nt = 0; nt < 4; ++nt) {
                const f32x4 sv = mfma_bf16(aqf[mt], bk[nt], (f32x4){0.f, 0.f, 0.f, 0.f});
                #pragma unroll
                for (int r = 0; r < 4; ++r) {
                    const float den = fmaxf(qr[r] * kn[nt], 1e-6f);
                    svf[nt][r] = sv[r] / den * ls + bmv[nt][r];
                }
            }

            // softmax across the 16-lane group (row = Q*4+r fixed per lane)
            float mx[4], sm[4];
            #pragma unroll
            for (int r = 0; r < 4; ++r) {
                float m = fmaxf(fmaxf(svf[0][r], svf[1][r]), fmaxf(svf[2][r], svf[3][r]));
                #pragma unroll
                for (int off = 1; off < 16; off <<= 1) m = fmaxf(m, __shfl_xor(m, off, 64));
                mx[r] = m; sm[r] = 0.f;
            }
            #pragma unroll
            for (int nt = 0; nt < 4; ++nt)
                #pragma unroll
                for (int r = 0; r < 4; ++r) {
                    const float e = __expf(svf[nt][r] - mx[r]);
                    svf[nt][r] = e; sm[r] += e;
                }
            #pragma unroll
            for (int r = 0; r < 4; ++r) {
                #pragma unroll
                for (int off = 1; off < 16; off <<= 1) sm[r] += __shfl_xor(sm[r], off, 64);
            }

            // Ps write (wave-private; visible after lgkmcnt, no barrier)
            #pragma unroll
            for (int nt = 0; nt < 4; ++nt)
                #pragma unroll
                for (int r = 0; r < 4; ++r)
                    Ps[(Q * 4 + r) * 72 + nt * 16 + t] = f2bf(svf[nt][r]);

            // PV
            f32x4 oa[2];
            oa[0] = (f32x4){0.f, 0.f, 0.f, 0.f};
            oa[1] = (f32x4){0.f, 0.f, 0.f, 0.f};
            #pragma unroll
            for (int st = 0; st < 2; ++st) {
                const short8 apf = *(const short8*)&Ps[t * 72 + st * 32 + Q * 8];
                #pragma unroll
                for (int n = 0; n < 2; ++n)
                    oa[n] = mfma_bf16(apf, vf[n][st], oa[n]);
            }

            float rsi[4];
            #pragma unroll
            for (int r = 0; r < 4; ++r) rsi[r] = 1.0f / sm[r];
            #pragma unroll
            for (int n = 0; n < 2; ++n)
                #pragma unroll
                for (int r = 0; r < 4; ++r)
                    out[((size_t)b * NTOK + mt * 16 + Q * 4 + r) * NC + h * 32 + n * 16 + t]
                        = oa[n][r] * rsi[r];
        }
    }
}

// ---------------------------------------------------------------------------
// proj: out = out @ wproj + bproj, in-place. 1152 blocks x 256. (unchanged)
// ---------------------------------------------------------------------------
__global__ __launch_bounds__(256) void proj_kernel(
    const unsigned short* __restrict__ wprojT, const float* __restrict__ bproj,
    float* __restrict__ out)
{
    __shared__ unsigned short as_[64 * 384];
    unsigned int* asu = (unsigned int*)as_;

    const int tid  = threadIdx.x;
    const size_t r0 = (size_t)blockIdx.x * 64;
    const int w    = tid >> 6;
    const int lane = tid & 63;
    const int quad = lane >> 4;
    const int lq   = lane & 15;

    {
        const int row = tid >> 2;
        const int q4  = tid & 3;
        const float* xr = &out[(r0 + row) * NC + q4 * 96];
        #pragma unroll
        for (int e = 0; e < 24; ++e) {
            const float4 xv = *(const float4*)&xr[e * 4];
            const int p = q4 * 48 + e * 2;
            const int g = p >> 2;
            const int u = row * 192 + (((g ^ (row & 7)) << 2) | (p & 3));
            uint2 w2;
            w2.x = pack2(xv.x, xv.y);
            w2.y = pack2(xv.z, xv.w);
            *(uint2*)&asu[u] = w2;
        }
    }
    __syncthreads();

    f32x4 acc[4][6];
    #pragma unroll
    for (int mt = 0; mt < 4; ++mt)
        #pragma unroll
        for (int n = 0; n < 6; ++n) acc[mt][n] = (f32x4){0.f, 0.f, 0.f, 0.f};

    const unsigned short* bp[6];
    #pragma unroll
    for (int n = 0; n < 6; ++n)
        bp[n] = wprojT + (size_t)(w * 96 + n * 16 + lq) * NC + quad * 8;

    for (int ksI = 0; ksI < 12; ++ksI) {
        short8 am[4];
        #pragma unroll
        for (int mt = 0; mt < 4; ++mt)
            am[mt] = tile_afrag(as_, mt * 16 + lq, ksI * 4 + quad);
        #pragma unroll
        for (int n = 0; n < 6; ++n) {
            const short8 bb = *(const short8*)&bp[n][ksI * 32];
            #pragma unroll
            for (int mt = 0; mt < 4; ++mt) acc[mt][n] = mfma_bf16(am[mt], bb, acc[mt][n]);
        }
    }

    float bpv[6];
    #pragma unroll
    for (int n = 0; n < 6; ++n) bpv[n] = bproj[w * 96 + n * 16 + lq];
    #pragma unroll
    for (int mt = 0; mt < 4; ++mt)
        #pragma unroll
        for (int n = 0; n < 6; ++n)
            #pragma unroll
            for (int r = 0; r < 4; ++r)
                out[(r0 + mt * 16 + quad * 4 + r) * NC + w * 96 + n * 16 + lq]
                    = acc[mt][n][r] + bpv[n];
}

// ---------------------------------------------------------------------------
extern "C" void kernel_launch(void* const* d_in, const int* in_sizes, int n_in,
                              void* d_out, int out_size, void* d_ws, size_t ws_size,
                              hipStream_t stream) {
    (void)in_sizes; (void)n_in; (void)out_size; (void)ws_size;
    const float* x     = (const float*)d_in[0];
    const float* mask  = (const float*)d_in[1];
    const float* wq    = (const float*)d_in[2];
    const float* bq    = (const float*)d_in[3];
    const float* wk    = (const float*)d_in[4];
    const float* wv    = (const float*)d_in[5];
    const float* bv    = (const float*)d_in[6];
    const float* w1    = (const float*)d_in[7];
    const float* b1    = (const float*)d_in[8];
    const float* w2    = (const float*)d_in[9];
    const float* b2    = (const float*)d_in[10];
    const float* tau   = (const float*)d_in[11];
    const float* wproj = (const float*)d_in[12];
    const float* bproj = (const float*)d_in[13];
    float* out = (float*)d_out;

    // ws: wT 884736 | wprojT 294912 | bias 196608 | tbs 10800  (~1.39 MB)
    unsigned short* wT     = (unsigned short*)d_ws;
    unsigned short* wprojT = (unsigned short*)((char*)d_ws + 884736);
    float*          bias   = (float*)((char*)d_ws + 884736 + 294912);
    float*          tbs    = (float*)((char*)d_ws + 884736 + 294912 + 196608);

    prep_kernel<<<1152, 256, 0, stream>>>(wq, wk, wv, wproj,
                                          (unsigned int*)wT, (unsigned int*)wprojT);
    cpb_mlp_kernel<<<225, 64, 0, stream>>>(w1, b1, w2, b2, tbs);
    bias_gather_kernel<<<48, 1024, 0, stream>>>(tbs, bias);
    attn_kernel<<<NB, 256, 0, stream>>>(x, mask, bq, bv, tau, wT, bias, out);
    proj_kernel<<<NB, 256, 0, stream>>>(wprojT, bproj, out);
}